// Round 1
// baseline (423.172 us; speedup 1.0000x reference)
//
#include <hip/hip_runtime.h>

// Problem: B=1024, H=512, E=512, V=50257, L=2 bidirectional GRU (1 step) + vocab projection + softmax.
// All inputs f32; hidden state input is zeros. Compute strategy: bf16 MFMA GEMMs with f32 accumulation.

#define Bsz 1024
#define Hs  512
#define Vv  50257
#define VP  50304          // V padded to multiple of 128 (393*128)
#define NG  1536           // 3*H
#define NPB 393            // VP/128

typedef __bf16 bf16x8 __attribute__((ext_vector_type(8)));
typedef float  floatx4 __attribute__((ext_vector_type(4)));

__device__ __forceinline__ unsigned short f2bf(float f) {
  unsigned int u = __builtin_bit_cast(unsigned int, f);
  u += 0x7fffu + ((u >> 16) & 1u);          // RNE
  return (unsigned short)(u >> 16);
}

// async global->LDS, 16B per lane. LDS dest is wave-uniform base + lane*16.
__device__ __forceinline__ void g2lds16(const void* g, void* l) {
  unsigned long long gv = (unsigned long long)g;
  unsigned int lv = (unsigned int)(unsigned long long)l;   // low 32 bits = LDS offset
  __builtin_amdgcn_global_load_lds(
      (const __attribute__((address_space(1))) unsigned int*)gv,
      (__attribute__((address_space(3))) unsigned int*)lv,
      16, 0, 0);
}

// ---------------- GEMM core: C(128x128 tile) = A(M x K) * B(N x K)^T, bf16 in, f32 acc --------
// 256 threads = 4 waves in 2x2; each wave does 64x64 via 4x4 frags of 16x16x32 MFMA.
// LDS tiles 128x64 bf16, XOR-swizzled (chunk ^= row&7) via pre-swizzled global source
// (global_load_lds writes linearly), reads apply the same swizzle -> conflict-free-ish ds_read_b128.
__device__ __forceinline__ void gemm_core(const unsigned short* A, const unsigned short* Bw, int K,
                                          int mt, int nt,
                                          unsigned short* Alds, unsigned short* Blds,
                                          floatx4 (&acc)[4][4]) {
  const int tid = threadIdx.x;
  const int w = tid >> 6, l = tid & 63;
  const int wr = w >> 1, wc = w & 1;
  const int g = l >> 4, r16 = l & 15;
  floatx4 zero = {0.f, 0.f, 0.f, 0.f};
#pragma unroll
  for (int i = 0; i < 4; ++i)
#pragma unroll
    for (int j = 0; j < 4; ++j) acc[i][j] = zero;

  const int nsteps = K >> 6;     // BK = 64
  for (int kt = 0; kt < nsteps; ++kt) {
    __syncthreads();             // protect LDS from previous iteration's readers
#pragma unroll
    for (int i = 0; i < 4; ++i) {
      int chunk = w * 4 + i;           // 16 chunks of 1KB per 16KB tile
      int t16 = chunk * 64 + l;        // 16B-slot index in tile
      int row = t16 >> 3, c = t16 & 7; // 8 slots per 128B row
      int sc = c ^ (row & 7);          // pre-swizzle the SOURCE so linear LDS holds swizzled layout
      const unsigned short* gA = A + (size_t)(mt * 128 + row) * K + kt * 64 + sc * 8;
      g2lds16(gA, (char*)Alds + chunk * 1024);
      const unsigned short* gB = Bw + (size_t)(nt * 128 + row) * K + kt * 64 + sc * 8;
      g2lds16(gB, (char*)Blds + chunk * 1024);
    }
    __syncthreads();             // compiler drains vmcnt(0) before s_barrier
#pragma unroll
    for (int ks = 0; ks < 2; ++ks) {
      bf16x8 a[4], b[4];
#pragma unroll
      for (int i = 0; i < 4; ++i) {
        int rowA = wr * 64 + i * 16 + r16;
        int ca = (ks * 4 + g) ^ (rowA & 7);
        a[i] = *(const bf16x8*)((const char*)Alds + rowA * 128 + ca * 16);
        int rowB = wc * 64 + i * 16 + r16;
        int cb = (ks * 4 + g) ^ (rowB & 7);
        b[i] = *(const bf16x8*)((const char*)Blds + rowB * 128 + cb * 16);
      }
#pragma unroll
      for (int i = 0; i < 4; ++i)
#pragma unroll
        for (int j = 0; j < 4; ++j)
          acc[i][j] = __builtin_amdgcn_mfma_f32_16x16x32_bf16(a[i], b[j], acc[i][j], 0, 0, 0);
    }
  }
}

// ---------------- batched GRU gate GEMMs (z = 0..3: {gi d0, gi d1, gh d0, gh d1}) -------------
struct GemmDesc {
  const unsigned short* A[4];
  const unsigned short* Bw[4];
  const float* bias[4];
  float* C[4];
  int K[4];
};

__global__ __launch_bounds__(256) void gemm_gru_batch(GemmDesc d) {
  __shared__ alignas(16) unsigned short Alds[128 * 64];
  __shared__ alignas(16) unsigned short Blds[128 * 64];
  const int z = blockIdx.z;
  floatx4 acc[4][4];
  gemm_core(d.A[z], d.Bw[z], d.K[z], blockIdx.y, blockIdx.x, Alds, Blds, acc);
  const float* bias = d.bias[z];
  float* C = d.C[z];
  const int tid = threadIdx.x, w = tid >> 6, l = tid & 63;
  const int wr = w >> 1, wc = w & 1, g = l >> 4, r16 = l & 15;
#pragma unroll
  for (int i = 0; i < 4; ++i)
#pragma unroll
    for (int j = 0; j < 4; ++j) {
      int col = blockIdx.x * 128 + wc * 64 + j * 16 + r16;
      float bc = bias[col];
#pragma unroll
      for (int q = 0; q < 4; ++q) {
        int row = blockIdx.y * 128 + wr * 64 + i * 16 + g * 4 + q;   // C layout: col=lane&15, row=(lane>>4)*4+q
        C[(size_t)row * NG + col] = acc[i][j][q] + bc;
      }
    }
}

// ---------------- projection GEMM with fused exp + per-block row partial sums ------------------
__global__ __launch_bounds__(256) void gemm_proj(const unsigned short* A, const unsigned short* Bw,
                                                 const float* biasp, float* probs, float* partial) {
  __shared__ alignas(16) unsigned short Alds[128 * 64];
  __shared__ alignas(16) unsigned short Blds[128 * 64];
  __shared__ float rowpart[128];
  const int tid = threadIdx.x;
  if (tid < 128) rowpart[tid] = 0.f;       // visible after first barrier inside gemm_core
  floatx4 acc[4][4];
  gemm_core(A, Bw, 512, blockIdx.y, blockIdx.x, Alds, Blds, acc);
  const int w = tid >> 6, l = tid & 63;
  const int wr = w >> 1, wc = w & 1, g = l >> 4, r16 = l & 15;
#pragma unroll
  for (int i = 0; i < 4; ++i)
#pragma unroll
    for (int q = 0; q < 4; ++q) {
      int row = blockIdx.y * 128 + wr * 64 + i * 16 + g * 4 + q;
      float s = 0.f;
#pragma unroll
      for (int j = 0; j < 4; ++j) {
        int col = blockIdx.x * 128 + wc * 64 + j * 16 + r16;
        float v = __expf(acc[i][j][q] + biasp[col]);   // pad cols: bias=-1e30 -> v=0
        if (col < Vv) probs[(size_t)row * Vv + col] = v;
        s += v;
      }
      s += __shfl_xor(s, 1); s += __shfl_xor(s, 2);
      s += __shfl_xor(s, 4); s += __shfl_xor(s, 8);
      if (r16 == 0) atomicAdd(&rowpart[wr * 64 + i * 16 + g * 4 + q], s);  // 2 commutative adds/row
    }
  __syncthreads();
  if (tid < 128) partial[(size_t)(blockIdx.y * 128 + tid) * NPB + blockIdx.x] = rowpart[tid];
}

// ---------------- elementwise GRU gates ---------------------------------------------------------
__global__ __launch_bounds__(256) void gru_gates(const float* Cbuf, const float* hidden,
                                                 float* out_newh, unsigned short* bf_out, int layer) {
  int idx = blockIdx.x * 256 + threadIdx.x;    // 2^20 total
  int j = idx & 511;
  int b = (idx >> 9) & 1023;
  int d = idx >> 19;
  const float* GI = Cbuf + (size_t)d * Bsz * NG;
  const float* GH = Cbuf + (size_t)(2 + d) * Bsz * NG;
  size_t base = (size_t)b * NG + j;
  float ir = GI[base], iz = GI[base + 512], inn = GI[base + 1024];
  float hr = GH[base], hz = GH[base + 512], hn = GH[base + 1024];
  float r = 1.f / (1.f + __expf(-(ir + hr)));
  float z = 1.f / (1.f + __expf(-(iz + hz)));
  float n = tanhf(inn + r * hn);
  size_t hoff = (size_t)(2 * layer + d) * (Bsz * Hs) + (size_t)b * Hs + j;
  float hprev = hidden[hoff];
  float h = (1.f - z) * n + z * hprev;
  out_newh[hoff] = h;
  if (layer == 0) {
    bf_out[(size_t)b * 1024 + d * 512 + j] = f2bf(h);     // inp1 = concat(hf, hb)
  } else if (d == 1) {
    bf_out[(size_t)b * 512 + j] = f2bf(h);                // hb1 feeds projection
  }
}

// ---------------- conversions ------------------------------------------------------------------
__global__ void convert_all(const float* Wih0, const float* Whh0, const float* Wih1, const float* Whh1,
                            const float* hidden, const float* Wproj, const float* bproj,
                            unsigned short* wih0b, unsigned short* whh0b, unsigned short* wih1b,
                            unsigned short* whh1b, unsigned short* hbf, unsigned short* wprojb,
                            float* bprojp) {
  long long idx = (long long)blockIdx.x * 256 + threadIdx.x;
  if (idx < 1572864) { wih0b[idx] = f2bf(Wih0[idx]); return; }
  idx -= 1572864;
  if (idx < 1572864) { whh0b[idx] = f2bf(Whh0[idx]); return; }
  idx -= 1572864;
  if (idx < 3145728) { wih1b[idx] = f2bf(Wih1[idx]); return; }
  idx -= 3145728;
  if (idx < 1572864) { whh1b[idx] = f2bf(Whh1[idx]); return; }
  idx -= 1572864;
  if (idx < 2097152) { hbf[idx] = f2bf(hidden[idx]); return; }
  idx -= 2097152;
  if (idx < 25755648) {          // Wproj padded [50304][512]
    long long row = idx >> 9, col = idx & 511;
    wprojb[idx] = (row < Vv) ? f2bf(Wproj[row * 512 + col]) : (unsigned short)0;
    return;
  }
  idx -= 25755648;
  if (idx < VP) { bprojp[idx] = (idx < Vv) ? bproj[idx] : -1e30f; return; }
}

__global__ void gather_embed(const int* x, const float* embed, unsigned short* xe) {
  int b = blockIdx.x, t = threadIdx.x;
  int tok = x[b];
  float2 v = *(const float2*)(embed + (size_t)tok * 512 + t * 2);
  unsigned int o = ((unsigned int)f2bf(v.y) << 16) | f2bf(v.x);
  *(unsigned int*)((unsigned short*)xe + (size_t)b * 512 + t * 2) = o;
}

// ---------------- softmax normalization --------------------------------------------------------
__global__ void rowsum_inv(const float* partial, float* inv) {
  int row = blockIdx.x, tid = threadIdx.x;   // 128 threads
  float s = 0.f;
  for (int c = tid; c < NPB; c += 128) s += partial[(size_t)row * NPB + c];
  __shared__ float tmp[128];
  tmp[tid] = s;
  __syncthreads();
  for (int off = 64; off > 0; off >>= 1) {
    if (tid < off) tmp[tid] += tmp[tid + off];
    __syncthreads();
  }
  if (tid == 0) inv[row] = 1.0f / tmp[0];
}

__global__ void scale_probs(float* probs, const float* inv) {
  int col = blockIdx.x * 256 + threadIdx.x;
  int row = blockIdx.y;
  if (col < Vv) probs[(size_t)row * Vv + col] *= inv[row];
}

// ---------------- host-side launch -------------------------------------------------------------
extern "C" void kernel_launch(void* const* d_in, const int* in_sizes, int n_in,
                              void* d_out, int out_size, void* d_ws, size_t ws_size,
                              hipStream_t stream) {
  const int*   x      = (const int*)d_in[0];
  const float* hidden = (const float*)d_in[1];
  const float* embed  = (const float*)d_in[2];
  const float* Wih0   = (const float*)d_in[3];
  const float* Whh0   = (const float*)d_in[4];
  const float* bih0   = (const float*)d_in[5];
  const float* bhh0   = (const float*)d_in[6];
  const float* Wih1   = (const float*)d_in[7];
  const float* Whh1   = (const float*)d_in[8];
  const float* bih1   = (const float*)d_in[9];
  const float* bhh1   = (const float*)d_in[10];
  const float* Wproj  = (const float*)d_in[11];
  const float* bproj  = (const float*)d_in[12];
  float* out = (float*)d_out;

  char* ws = (char*)d_ws;
  unsigned short* wih0b  = (unsigned short*)(ws);
  unsigned short* whh0b  = (unsigned short*)(ws + 3145728);
  unsigned short* wih1b  = (unsigned short*)(ws + 6291456);
  unsigned short* whh1b  = (unsigned short*)(ws + 12582912);
  unsigned short* hbf    = (unsigned short*)(ws + 15728640);
  unsigned short* wprojb = (unsigned short*)(ws + 19922944);
  float*          bprojp = (float*)(ws + 71434240);
  unsigned short* xe     = (unsigned short*)(ws + 71635456);
  unsigned short* inp1   = (unsigned short*)(ws + 72684032);
  unsigned short* hb1    = (unsigned short*)(ws + 74781184);
  float*          Cbuf   = (float*)(ws + 75829760);
  float*          partial= (float*)(ws + 100995584);
  float*          inv    = (float*)(ws + 102605312);

  float* out_newh = out + 51463168ll;   // 1024*50257

  convert_all<<<139717, 256, 0, stream>>>(Wih0, Whh0, Wih1, Whh1, hidden, Wproj, bproj,
                                          wih0b, whh0b, wih1b, whh1b, hbf, wprojb, bprojp);
  gather_embed<<<1024, 256, 0, stream>>>(x, embed, xe);

  // layer 0
  GemmDesc d0;
  d0.A[0] = xe;  d0.A[1] = xe;
  d0.A[2] = hbf; d0.A[3] = hbf + 524288;
  d0.Bw[0] = wih0b; d0.Bw[1] = wih0b + 786432;
  d0.Bw[2] = whh0b; d0.Bw[3] = whh0b + 786432;
  d0.bias[0] = bih0; d0.bias[1] = bih0 + 1536;
  d0.bias[2] = bhh0; d0.bias[3] = bhh0 + 1536;
  d0.C[0] = Cbuf;             d0.C[1] = Cbuf + 1572864;
  d0.C[2] = Cbuf + 2*1572864; d0.C[3] = Cbuf + 3*1572864;
  d0.K[0] = d0.K[1] = d0.K[2] = d0.K[3] = 512;
  gemm_gru_batch<<<dim3(12, 8, 4), 256, 0, stream>>>(d0);
  gru_gates<<<4096, 256, 0, stream>>>(Cbuf, hidden, out_newh, inp1, 0);

  // layer 1
  GemmDesc d1;
  d1.A[0] = inp1; d1.A[1] = inp1;
  d1.A[2] = hbf + 2*524288; d1.A[3] = hbf + 3*524288;
  d1.Bw[0] = wih1b; d1.Bw[1] = wih1b + 1572864;
  d1.Bw[2] = whh1b; d1.Bw[3] = whh1b + 786432;
  d1.bias[0] = bih1; d1.bias[1] = bih1 + 1536;
  d1.bias[2] = bhh1; d1.bias[3] = bhh1 + 1536;
  d1.C[0] = Cbuf;             d1.C[1] = Cbuf + 1572864;
  d1.C[2] = Cbuf + 2*1572864; d1.C[3] = Cbuf + 3*1572864;
  d1.K[0] = d1.K[1] = 1024; d1.K[2] = d1.K[3] = 512;
  gemm_gru_batch<<<dim3(12, 8, 4), 256, 0, stream>>>(d1);
  gru_gates<<<4096, 256, 0, stream>>>(Cbuf, hidden, out_newh, hb1, 1);

  // projection + softmax
  gemm_proj<<<dim3(NPB, 8), 256, 0, stream>>>(hb1, wprojb, bprojp, out, partial);
  rowsum_inv<<<1024, 128, 0, stream>>>(partial, inv);
  scale_probs<<<dim3(197, 1024), 256, 0, stream>>>(out, inv);
}

// Round 2
// 327.693 us; speedup vs baseline: 1.2914x; 1.2914x over previous
//
#include <hip/hip_runtime.h>

// B=1024, H=512, E=512, V=50257, L=2 bidirectional GRU (1 step) + vocab projection + softmax.
// bf16 MFMA GEMMs (256x128 tile, 8 waves), f32 accum. Softmax via bf16 exp-stash + scale pass.

#define Bsz 1024
#define Hs  512
#define Vv  50257
#define VP  50304          // V padded to multiple of 128 (393*128)
#define NG  1536           // 3*H
#define NPB 393            // VP/128

typedef __bf16 bf16x8 __attribute__((ext_vector_type(8)));
typedef float  floatx4 __attribute__((ext_vector_type(4)));

__device__ __forceinline__ unsigned short f2bf(float f) {
  unsigned int u = __builtin_bit_cast(unsigned int, f);
  u += 0x7fffu + ((u >> 16) & 1u);          // RNE
  return (unsigned short)(u >> 16);
}

__device__ __forceinline__ void cvt4(const float* src, unsigned short* dst) {
  float4 f = *(const float4*)src;
  unsigned int lo = (unsigned int)f2bf(f.x) | ((unsigned int)f2bf(f.y) << 16);
  unsigned int hi = (unsigned int)f2bf(f.z) | ((unsigned int)f2bf(f.w) << 16);
  *(uint2*)dst = make_uint2(lo, hi);
}

// async global->LDS, 16B per lane. LDS dest is wave-uniform base + lane*16.
__device__ __forceinline__ void g2lds16(const void* g, void* l) {
  unsigned long long gv = (unsigned long long)g;
  unsigned int lv = (unsigned int)(unsigned long long)l;
  __builtin_amdgcn_global_load_lds(
      (const __attribute__((address_space(1))) unsigned int*)gv,
      (__attribute__((address_space(3))) unsigned int*)lv,
      16, 0, 0);
}

// ---------------- GEMM core: C(256x128 tile) = A * B^T, bf16 in, f32 acc ----------------------
// 512 threads = 8 waves (4 row-quadrants x 2 col-halves); each wave 64x64 via 4x4 frags of
// 16x16x32 MFMA. LDS: A 256x64 (32KB), B 128x64 (16KB), XOR-swizzled via pre-swizzled global src.
__device__ __forceinline__ void gemm_core8(const unsigned short* A, const unsigned short* Bw, int K,
                                           int mt, int nt,
                                           unsigned short* Alds, unsigned short* Blds,
                                           floatx4 (&acc)[4][4]) {
  const int tid = threadIdx.x;
  const int w = tid >> 6, l = tid & 63;
  const int wr = w >> 1, wc = w & 1;
  const int g = l >> 4, r16 = l & 15;
  floatx4 zero = {0.f, 0.f, 0.f, 0.f};
#pragma unroll
  for (int i = 0; i < 4; ++i)
#pragma unroll
    for (int j = 0; j < 4; ++j) acc[i][j] = zero;

  const int nsteps = K >> 6;     // BK = 64
  for (int kt = 0; kt < nsteps; ++kt) {
    __syncthreads();             // protect LDS from previous iteration's readers
#pragma unroll
    for (int i = 0; i < 4; ++i) {            // A: 32 chunks of 1KB
      int chunk = w * 4 + i;
      int t16 = chunk * 64 + l;
      int row = t16 >> 3, c = t16 & 7;
      int sc = c ^ (row & 7);
      g2lds16(A + (size_t)(mt * 256 + row) * K + kt * 64 + sc * 8, (char*)Alds + chunk * 1024);
    }
#pragma unroll
    for (int i = 0; i < 2; ++i) {            // B: 16 chunks of 1KB
      int chunk = w * 2 + i;
      int t16 = chunk * 64 + l;
      int row = t16 >> 3, c = t16 & 7;
      int sc = c ^ (row & 7);
      g2lds16(Bw + (size_t)(nt * 128 + row) * K + kt * 64 + sc * 8, (char*)Blds + chunk * 1024);
    }
    __syncthreads();             // drains vmcnt(0) before s_barrier
#pragma unroll
    for (int ks = 0; ks < 2; ++ks) {
      bf16x8 a[4], b[4];
#pragma unroll
      for (int i = 0; i < 4; ++i) {
        int rowA = wr * 64 + i * 16 + r16;
        int ca = (ks * 4 + g) ^ (rowA & 7);
        a[i] = *(const bf16x8*)((const char*)Alds + rowA * 128 + ca * 16);
        int rowB = wc * 64 + i * 16 + r16;
        int cb = (ks * 4 + g) ^ (rowB & 7);
        b[i] = *(const bf16x8*)((const char*)Blds + rowB * 128 + cb * 16);
      }
#pragma unroll
      for (int i = 0; i < 4; ++i)
#pragma unroll
        for (int j = 0; j < 4; ++j)
          acc[i][j] = __builtin_amdgcn_mfma_f32_16x16x32_bf16(a[i], b[j], acc[i][j], 0, 0, 0);
    }
  }
}

// ---------------- batched GRU gate GEMMs (z = 0..3: {gi d0, gi d1, gh d0, gh d1}) -------------
struct GemmDesc {
  const unsigned short* A[4];
  const unsigned short* Bw[4];
  const float* bias[4];
  float* C[4];
  int K[4];
};

__global__ __launch_bounds__(512, 4) void gemm_gru_batch(GemmDesc d) {
  __shared__ alignas(16) unsigned short Alds[256 * 64];
  __shared__ alignas(16) unsigned short Blds[128 * 64];
  const int z = blockIdx.z;
  floatx4 acc[4][4];
  gemm_core8(d.A[z], d.Bw[z], d.K[z], blockIdx.y, blockIdx.x, Alds, Blds, acc);
  const float* bias = d.bias[z];
  float* C = d.C[z];
  const int tid = threadIdx.x, w = tid >> 6, l = tid & 63;
  const int wr = w >> 1, wc = w & 1, g = l >> 4, r16 = l & 15;
#pragma unroll
  for (int i = 0; i < 4; ++i)
#pragma unroll
    for (int j = 0; j < 4; ++j) {
      int col = blockIdx.x * 128 + wc * 64 + j * 16 + r16;
      float bc = bias[col];
#pragma unroll
      for (int q = 0; q < 4; ++q) {
        int row = blockIdx.y * 256 + wr * 64 + i * 16 + g * 4 + q;
        C[(size_t)row * NG + col] = acc[i][j][q] + bc;
      }
    }
}

// ---------------- projection GEMM ---------------------------------------------------------------
// MODE 0: exp -> bf16 stash + row partial sums.  MODE 1: partial sums only.
// MODE 2: exp * inv[row] -> f32 probs (recompute fallback).
template <int MODE>
__global__ __launch_bounds__(512, 4) void gemm_proj(const unsigned short* A, const unsigned short* Bw,
                                                    const float* biasp, unsigned short* stash,
                                                    float* probs, float* partial, const float* inv) {
  __shared__ alignas(16) unsigned short Alds[256 * 64];
  __shared__ alignas(16) unsigned short Blds[128 * 64];
  __shared__ float rowpart[256];
  const int tid = threadIdx.x;
  if (MODE != 2 && tid < 256) rowpart[tid] = 0.f;
  // bijective XCD-chunk swizzle: nwg=1572, q=196, r=4
  int orig = blockIdx.x;
  int xcd = orig & 7, slot = orig >> 3;
  int wgid = (xcd < 4 ? xcd * 197 : 788 + (xcd - 4) * 196) + slot;
  int mt = wgid & 3, nt = wgid >> 2;
  floatx4 acc[4][4];
  gemm_core8(A, Bw, 512, mt, nt, Alds, Blds, acc);
  const int w = tid >> 6, l = tid & 63;
  const int wr = w >> 1, wc = w & 1, g = l >> 4, r16 = l & 15;
  float bcol[4];
#pragma unroll
  for (int j = 0; j < 4; ++j) bcol[j] = biasp[nt * 128 + wc * 64 + j * 16 + r16];
#pragma unroll
  for (int i = 0; i < 4; ++i)
#pragma unroll
    for (int q = 0; q < 4; ++q) {
      int rowl = wr * 64 + i * 16 + g * 4 + q;
      int grow = mt * 256 + rowl;
      float rinv = (MODE == 2) ? inv[grow] : 0.f;
      float s = 0.f;
#pragma unroll
      for (int j = 0; j < 4; ++j) {
        int col = nt * 128 + wc * 64 + j * 16 + r16;
        float v = __expf(acc[i][j][q] + bcol[j]);     // pad cols: bias=-1e30 -> v=0
        if (MODE == 0) stash[(size_t)grow * VP + col] = f2bf(v);
        if (MODE == 2) { if (col < Vv) probs[(size_t)grow * Vv + col] = v * rinv; }
        s += v;
      }
      if (MODE != 2) {
        s += __shfl_xor(s, 1); s += __shfl_xor(s, 2);
        s += __shfl_xor(s, 4); s += __shfl_xor(s, 8);
        if (r16 == 0) atomicAdd(&rowpart[rowl], s);   // 2 commutative adds per row: deterministic
      }
    }
  if (MODE != 2) {
    __syncthreads();
    if (tid < 256) partial[(size_t)(mt * 256 + tid) * NPB + nt] = rowpart[tid];
  }
}

// ---------------- elementwise GRU gates ---------------------------------------------------------
__global__ __launch_bounds__(256) void gru_gates(const float* Cbuf, const float* hidden,
                                                 float* out_newh, unsigned short* bf_out, int layer) {
  int idx = blockIdx.x * 256 + threadIdx.x;    // 2^20 total
  int j = idx & 511;
  int b = (idx >> 9) & 1023;
  int d = idx >> 19;
  const float* GI = Cbuf + (size_t)d * Bsz * NG;
  const float* GH = Cbuf + (size_t)(2 + d) * Bsz * NG;
  size_t base = (size_t)b * NG + j;
  float ir = GI[base], iz = GI[base + 512], inn = GI[base + 1024];
  float hr = GH[base], hz = GH[base + 512], hn = GH[base + 1024];
  float r = 1.f / (1.f + __expf(-(ir + hr)));
  float z = 1.f / (1.f + __expf(-(iz + hz)));
  float n = tanhf(inn + r * hn);
  size_t hoff = (size_t)(2 * layer + d) * (Bsz * Hs) + (size_t)b * Hs + j;
  float hprev = hidden[hoff];
  float h = (1.f - z) * n + z * hprev;
  out_newh[hoff] = h;
  if (layer == 0) {
    bf_out[(size_t)b * 1024 + d * 512 + j] = f2bf(h);     // inp1 = concat(hf, hb)
  } else if (d == 1) {
    bf_out[(size_t)b * 512 + j] = f2bf(h);                // hb1 feeds projection
  }
}

// ---------------- conversions (vectorized x4) ---------------------------------------------------
__global__ void convert_all(const float* Wih0, const float* Whh0, const float* Wih1, const float* Whh1,
                            const float* hidden, const float* Wproj, const float* bproj,
                            unsigned short* wih0b, unsigned short* whh0b, unsigned short* wih1b,
                            unsigned short* whh1b, unsigned short* hbf, unsigned short* wprojb,
                            float* bprojp) {
  long long idx = ((long long)blockIdx.x * 256 + threadIdx.x) * 4;
  if (idx < 1572864) { cvt4(Wih0 + idx, wih0b + idx); return; }
  idx -= 1572864;
  if (idx < 1572864) { cvt4(Whh0 + idx, whh0b + idx); return; }
  idx -= 1572864;
  if (idx < 3145728) { cvt4(Wih1 + idx, wih1b + idx); return; }
  idx -= 3145728;
  if (idx < 1572864) { cvt4(Whh1 + idx, whh1b + idx); return; }
  idx -= 1572864;
  if (idx < 2097152) { cvt4(hidden + idx, hbf + idx); return; }
  idx -= 2097152;
  if (idx < 25755648) {          // Wproj padded [50304][512]
    long long row = idx >> 9, col = idx & 511;
    if (row < Vv) cvt4(Wproj + row * 512 + col, wprojb + idx);
    else *(uint2*)(wprojb + idx) = make_uint2(0u, 0u);
    return;
  }
  idx -= 25755648;
  if (idx < VP) {
    float4 v;
    v.x = (idx + 0 < Vv) ? bproj[idx + 0] : -1e30f;
    v.y = (idx + 1 < Vv) ? bproj[idx + 1] : -1e30f;
    v.z = (idx + 2 < Vv) ? bproj[idx + 2] : -1e30f;
    v.w = (idx + 3 < Vv) ? bproj[idx + 3] : -1e30f;
    *(float4*)(bprojp + idx) = v;
  }
}

__global__ void gather_embed(const int* x, const float* embed, unsigned short* xe) {
  int b = blockIdx.x, t = threadIdx.x;
  int tok = x[b];
  float2 v = *(const float2*)(embed + (size_t)tok * 512 + t * 2);
  unsigned int o = ((unsigned int)f2bf(v.y) << 16) | f2bf(v.x);
  *(unsigned int*)((unsigned short*)xe + (size_t)b * 512 + t * 2) = o;
}

// ---------------- softmax normalization --------------------------------------------------------
__global__ void rowsum_inv(const float* partial, float* inv) {
  int row = blockIdx.x, tid = threadIdx.x;   // 128 threads
  float s = 0.f;
  for (int c = tid; c < NPB; c += 128) s += partial[(size_t)row * NPB + c];
  __shared__ float tmp[128];
  tmp[tid] = s;
  __syncthreads();
  for (int off = 64; off > 0; off >>= 1) {
    if (tid < off) tmp[tid] += tmp[tid + off];
    __syncthreads();
  }
  if (tid == 0) inv[row] = 1.0f / tmp[0];
}

__global__ void scale_expand(const unsigned short* stash, const float* inv, float* probs) {
  int t = blockIdx.x * 256 + threadIdx.x;
  int row = blockIdx.y;
  int col0 = t * 8;
  if (col0 >= VP) return;
  float s = inv[row];
  bf16x8 v = *(const bf16x8*)(stash + (size_t)row * VP + col0);
  float* o = probs + (size_t)row * Vv + col0;
#pragma unroll
  for (int k = 0; k < 8; ++k) {
    if (col0 + k < Vv) o[k] = (float)v[k] * s;
  }
}

// ---------------- host-side launch -------------------------------------------------------------
extern "C" void kernel_launch(void* const* d_in, const int* in_sizes, int n_in,
                              void* d_out, int out_size, void* d_ws, size_t ws_size,
                              hipStream_t stream) {
  const int*   x      = (const int*)d_in[0];
  const float* hidden = (const float*)d_in[1];
  const float* embed  = (const float*)d_in[2];
  const float* Wih0   = (const float*)d_in[3];
  const float* Whh0   = (const float*)d_in[4];
  const float* bih0   = (const float*)d_in[5];
  const float* bhh0   = (const float*)d_in[6];
  const float* Wih1   = (const float*)d_in[7];
  const float* Whh1   = (const float*)d_in[8];
  const float* bih1   = (const float*)d_in[9];
  const float* bhh1   = (const float*)d_in[10];
  const float* Wproj  = (const float*)d_in[11];
  const float* bproj  = (const float*)d_in[12];
  float* out = (float*)d_out;

  char* ws = (char*)d_ws;
  unsigned short* wih0b  = (unsigned short*)(ws);
  unsigned short* whh0b  = (unsigned short*)(ws + 3145728);
  unsigned short* wih1b  = (unsigned short*)(ws + 6291456);
  unsigned short* whh1b  = (unsigned short*)(ws + 12582912);
  unsigned short* hbf    = (unsigned short*)(ws + 15728640);
  unsigned short* wprojb = (unsigned short*)(ws + 19922944);
  float*          bprojp = (float*)(ws + 71434240);
  unsigned short* xe     = (unsigned short*)(ws + 71635456);
  unsigned short* inp1   = (unsigned short*)(ws + 72684032);
  unsigned short* hb1    = (unsigned short*)(ws + 74781184);
  float*          Cbuf   = (float*)(ws + 75829760);
  float*          partial= (float*)(ws + 100995584);
  float*          inv    = (float*)(ws + 102605312);
  unsigned short* stash  = (unsigned short*)(ws + 102609408);
  const size_t NEED_STASH = 102609408ull + (size_t)Bsz * VP * 2ull;   // ~205.6 MB

  float* out_newh = out + 51463168ll;   // 1024*50257

  convert_all<<<34930, 256, 0, stream>>>(Wih0, Whh0, Wih1, Whh1, hidden, Wproj, bproj,
                                         wih0b, whh0b, wih1b, whh1b, hbf, wprojb, bprojp);
  gather_embed<<<1024, 256, 0, stream>>>(x, embed, xe);

  // layer 0
  GemmDesc d0;
  d0.A[0] = xe;  d0.A[1] = xe;
  d0.A[2] = hbf; d0.A[3] = hbf + 524288;
  d0.Bw[0] = wih0b; d0.Bw[1] = wih0b + 786432;
  d0.Bw[2] = whh0b; d0.Bw[3] = whh0b + 786432;
  d0.bias[0] = bih0; d0.bias[1] = bih0 + 1536;
  d0.bias[2] = bhh0; d0.bias[3] = bhh0 + 1536;
  d0.C[0] = Cbuf;             d0.C[1] = Cbuf + 1572864;
  d0.C[2] = Cbuf + 2*1572864; d0.C[3] = Cbuf + 3*1572864;
  d0.K[0] = d0.K[1] = d0.K[2] = d0.K[3] = 512;
  gemm_gru_batch<<<dim3(12, 4, 4), 512, 0, stream>>>(d0);
  gru_gates<<<4096, 256, 0, stream>>>(Cbuf, hidden, out_newh, inp1, 0);

  // layer 1
  GemmDesc d1;
  d1.A[0] = inp1; d1.A[1] = inp1;
  d1.A[2] = hbf + 2*524288; d1.A[3] = hbf + 3*524288;
  d1.Bw[0] = wih1b; d1.Bw[1] = wih1b + 1572864;
  d1.Bw[2] = whh1b; d1.Bw[3] = whh1b + 786432;
  d1.bias[0] = bih1; d1.bias[1] = bih1 + 1536;
  d1.bias[2] = bhh1; d1.bias[3] = bhh1 + 1536;
  d1.C[0] = Cbuf;             d1.C[1] = Cbuf + 1572864;
  d1.C[2] = Cbuf + 2*1572864; d1.C[3] = Cbuf + 3*1572864;
  d1.K[0] = d1.K[1] = 1024; d1.K[2] = d1.K[3] = 512;
  gemm_gru_batch<<<dim3(12, 4, 4), 512, 0, stream>>>(d1);
  gru_gates<<<4096, 256, 0, stream>>>(Cbuf, hidden, out_newh, hb1, 1);

  // projection + softmax
  if (ws_size >= NEED_STASH) {
    gemm_proj<0><<<1572, 512, 0, stream>>>(hb1, wprojb, bprojp, stash, out, partial, inv);
    rowsum_inv<<<1024, 128, 0, stream>>>(partial, inv);
    scale_expand<<<dim3(25, 1024), 256, 0, stream>>>(stash, inv, out);
  } else {
    gemm_proj<1><<<1572, 512, 0, stream>>>(hb1, wprojb, bprojp, stash, out, partial, inv);
    rowsum_inv<<<1024, 128, 0, stream>>>(partial, inv);
    gemm_proj<2><<<1572, 512, 0, stream>>>(hb1, wprojb, bprojp, stash, out, partial, inv);
  }
}

// Round 3
// 252.634 us; speedup vs baseline: 1.6750x; 1.2971x over previous
//
#include <hip/hip_runtime.h>

// B=1024, H=512, E=512, V=50257, L=2 bidirectional GRU (1 step) + vocab projection + softmax.
// bf16 MFMA GEMMs (256x128 tile, 8 waves), f32 accum. Softmax via bf16 exp-stash + scale pass.

#define Bsz 1024
#define Hs  512
#define Vv  50257
#define VP  50304          // V padded to multiple of 128 (393*128)
#define NG  1536           // 3*H
#define NPB 393            // VP/128

typedef __bf16 bf16x8 __attribute__((ext_vector_type(8)));
typedef float  floatx4 __attribute__((ext_vector_type(4)));

__device__ __forceinline__ unsigned short f2bf(float f) {
  unsigned int u = __builtin_bit_cast(unsigned int, f);
  u += 0x7fffu + ((u >> 16) & 1u);          // RNE
  return (unsigned short)(u >> 16);
}

__device__ __forceinline__ float bf2f(unsigned short u) {
  unsigned int x = (unsigned int)u << 16;
  return __builtin_bit_cast(float, x);
}

__device__ __forceinline__ void cvt4(const float* src, unsigned short* dst) {
  float4 f = *(const float4*)src;
  unsigned int lo = (unsigned int)f2bf(f.x) | ((unsigned int)f2bf(f.y) << 16);
  unsigned int hi = (unsigned int)f2bf(f.z) | ((unsigned int)f2bf(f.w) << 16);
  *(uint2*)dst = make_uint2(lo, hi);
}

// async global->LDS, 16B per lane. LDS dest is wave-uniform base + lane*16.
__device__ __forceinline__ void g2lds16(const void* g, void* l) {
  unsigned long long gv = (unsigned long long)g;
  unsigned int lv = (unsigned int)(unsigned long long)l;
  __builtin_amdgcn_global_load_lds(
      (const __attribute__((address_space(1))) unsigned int*)gv,
      (__attribute__((address_space(3))) unsigned int*)lv,
      16, 0, 0);
}

// ---------------- GEMM core: C(256x128 tile) = A * B^T, bf16 in, f32 acc ----------------------
// 512 threads = 8 waves; each wave 64x64 via 4x4 frags of 16x16x32 MFMA.
// LDS: A 256x64 (32KB), B 128x64 (16KB), XOR-swizzled via pre-swizzled global src.
__device__ __forceinline__ void gemm_core8(const unsigned short* A, const unsigned short* Bw, int K,
                                           int mt, int nt,
                                           unsigned short* Alds, unsigned short* Blds,
                                           floatx4 (&acc)[4][4]) {
  const int tid = threadIdx.x;
  const int w = tid >> 6, l = tid & 63;
  const int wr = w >> 1, wc = w & 1;
  const int g = l >> 4, r16 = l & 15;
  floatx4 zero = {0.f, 0.f, 0.f, 0.f};
#pragma unroll
  for (int i = 0; i < 4; ++i)
#pragma unroll
    for (int j = 0; j < 4; ++j) acc[i][j] = zero;

  const int nsteps = K >> 6;     // BK = 64
  for (int kt = 0; kt < nsteps; ++kt) {
    __syncthreads();             // protect LDS from previous iteration's readers
#pragma unroll
    for (int i = 0; i < 4; ++i) {            // A: 32 chunks of 1KB
      int chunk = w * 4 + i;
      int t16 = chunk * 64 + l;
      int row = t16 >> 3, c = t16 & 7;
      int sc = c ^ (row & 7);
      g2lds16(A + (size_t)(mt * 256 + row) * K + kt * 64 + sc * 8, (char*)Alds + chunk * 1024);
    }
#pragma unroll
    for (int i = 0; i < 2; ++i) {            // B: 16 chunks of 1KB
      int chunk = w * 2 + i;
      int t16 = chunk * 64 + l;
      int row = t16 >> 3, c = t16 & 7;
      int sc = c ^ (row & 7);
      g2lds16(Bw + (size_t)(nt * 128 + row) * K + kt * 64 + sc * 8, (char*)Blds + chunk * 1024);
    }
    __syncthreads();             // drains vmcnt(0) before s_barrier
#pragma unroll
    for (int ks = 0; ks < 2; ++ks) {
      bf16x8 a[4], b[4];
#pragma unroll
      for (int i = 0; i < 4; ++i) {
        int rowA = wr * 64 + i * 16 + r16;
        int ca = (ks * 4 + g) ^ (rowA & 7);
        a[i] = *(const bf16x8*)((const char*)Alds + rowA * 128 + ca * 16);
        int rowB = wc * 64 + i * 16 + r16;
        int cb = (ks * 4 + g) ^ (rowB & 7);
        b[i] = *(const bf16x8*)((const char*)Blds + rowB * 128 + cb * 16);
      }
#pragma unroll
      for (int i = 0; i < 4; ++i)
#pragma unroll
        for (int j = 0; j < 4; ++j)
          acc[i][j] = __builtin_amdgcn_mfma_f32_16x16x32_bf16(a[i], b[j], acc[i][j], 0, 0, 0);
    }
  }
}

// ---------------- batched GRU gate GEMMs (z = 0..3: {gi d0, gi d1, gh d0, gh d1}) -------------
struct GemmDesc {
  const unsigned short* A[4];
  const unsigned short* Bw[4];
  const float* bias[4];
  float* C[4];
  int K[4];
};

__global__ __launch_bounds__(512, 4) void gemm_gru_batch(GemmDesc d) {
  __shared__ alignas(16) unsigned short Alds[256 * 64];
  __shared__ alignas(16) unsigned short Blds[128 * 64];
  const int z = blockIdx.z;
  floatx4 acc[4][4];
  gemm_core8(d.A[z], d.Bw[z], d.K[z], blockIdx.y, blockIdx.x, Alds, Blds, acc);
  const float* bias = d.bias[z];
  float* C = d.C[z];
  const int tid = threadIdx.x, w = tid >> 6, l = tid & 63;
  const int wr = w >> 1, wc = w & 1, g = l >> 4, r16 = l & 15;
#pragma unroll
  for (int i = 0; i < 4; ++i)
#pragma unroll
    for (int j = 0; j < 4; ++j) {
      int col = blockIdx.x * 128 + wc * 64 + j * 16 + r16;
      float bc = bias[col];
#pragma unroll
      for (int q = 0; q < 4; ++q) {
        int row = blockIdx.y * 256 + wr * 64 + i * 16 + g * 4 + q;
        C[(size_t)row * NG + col] = acc[i][j][q] + bc;
      }
    }
}

// ---------------- projection GEMM ---------------------------------------------------------------
// MODE 0: exp -> bf16 stash + row partial sums.  MODE 1: partial sums only.
// MODE 2: exp * inv[row] -> f32 probs (recompute fallback).
template <int MODE>
__global__ __launch_bounds__(512, 4) void gemm_proj(const unsigned short* A, const unsigned short* Bw,
                                                    const float* biasp, unsigned short* stash,
                                                    float* probs, float* partial, const float* inv) {
  __shared__ alignas(16) unsigned short Alds[256 * 64];
  __shared__ alignas(16) unsigned short Blds[128 * 64];
  __shared__ float rowpart[256];
  const int tid = threadIdx.x;
  if (MODE != 2 && tid < 256) rowpart[tid] = 0.f;
  // bijective XCD-chunk swizzle: nwg=1572, q=196, r=4
  int orig = blockIdx.x;
  int xcd = orig & 7, slot = orig >> 3;
  int wgid = (xcd < 4 ? xcd * 197 : 788 + (xcd - 4) * 196) + slot;
  int mt = wgid & 3, nt = wgid >> 2;
  floatx4 acc[4][4];
  gemm_core8(A, Bw, 512, mt, nt, Alds, Blds, acc);
  const int w = tid >> 6, l = tid & 63;
  const int wr = w >> 1, wc = w & 1, g = l >> 4, r16 = l & 15;
  float bcol[4];
#pragma unroll
  for (int j = 0; j < 4; ++j) bcol[j] = biasp[nt * 128 + wc * 64 + j * 16 + r16];
#pragma unroll
  for (int i = 0; i < 4; ++i)
#pragma unroll
    for (int q = 0; q < 4; ++q) {
      int rowl = wr * 64 + i * 16 + g * 4 + q;
      int grow = mt * 256 + rowl;
      float rinv = (MODE == 2) ? inv[grow] : 0.f;
      float s = 0.f;
#pragma unroll
      for (int j = 0; j < 4; ++j) {
        int col = nt * 128 + wc * 64 + j * 16 + r16;
        float v = __expf(acc[i][j][q] + bcol[j]);     // pad cols: bias=-1e30 -> v=0
        if (MODE == 0) stash[(size_t)grow * VP + col] = f2bf(v);
        if (MODE == 2) { if (col < Vv) probs[(size_t)grow * Vv + col] = v * rinv; }
        s += v;
      }
      if (MODE != 2) {
        s += __shfl_xor(s, 1); s += __shfl_xor(s, 2);
        s += __shfl_xor(s, 4); s += __shfl_xor(s, 8);
        if (r16 == 0) atomicAdd(&rowpart[rowl], s);   // 2 commutative adds per row: deterministic
      }
    }
  if (MODE != 2) {
    __syncthreads();
    if (tid < 256) partial[(size_t)(mt * 256 + tid) * NPB + nt] = rowpart[tid];
  }
}

// ---------------- elementwise GRU gates ---------------------------------------------------------
__global__ __launch_bounds__(256) void gru_gates(const float* Cbuf, const float* hidden,
                                                 float* out_newh, unsigned short* bf_out, int layer) {
  int idx = blockIdx.x * 256 + threadIdx.x;    // 2^20 total
  int j = idx & 511;
  int b = (idx >> 9) & 1023;
  int d = idx >> 19;
  const float* GI = Cbuf + (size_t)d * Bsz * NG;
  const float* GH = Cbuf + (size_t)(2 + d) * Bsz * NG;
  size_t base = (size_t)b * NG + j;
  float ir = GI[base], iz = GI[base + 512], inn = GI[base + 1024];
  float hr = GH[base], hz = GH[base + 512], hn = GH[base + 1024];
  float r = 1.f / (1.f + __expf(-(ir + hr)));
  float z = 1.f / (1.f + __expf(-(iz + hz)));
  float n = tanhf(inn + r * hn);
  size_t hoff = (size_t)(2 * layer + d) * (Bsz * Hs) + (size_t)b * Hs + j;
  float hprev = hidden[hoff];
  float h = (1.f - z) * n + z * hprev;
  out_newh[hoff] = h;
  if (layer == 0) {
    bf_out[(size_t)b * 1024 + d * 512 + j] = f2bf(h);     // inp1 = concat(hf, hb)
  } else if (d == 1) {
    bf_out[(size_t)b * 512 + j] = f2bf(h);                // hb1 feeds projection
  }
}

// ---------------- conversions (vectorized x4) ---------------------------------------------------
__global__ void convert_all(const float* Wih0, const float* Whh0, const float* Wih1, const float* Whh1,
                            const float* hidden, const float* Wproj, const float* bproj,
                            unsigned short* wih0b, unsigned short* whh0b, unsigned short* wih1b,
                            unsigned short* whh1b, unsigned short* hbf, unsigned short* wprojb,
                            float* bprojp) {
  long long idx = ((long long)blockIdx.x * 256 + threadIdx.x) * 4;
  if (idx < 1572864) { cvt4(Wih0 + idx, wih0b + idx); return; }
  idx -= 1572864;
  if (idx < 1572864) { cvt4(Whh0 + idx, whh0b + idx); return; }
  idx -= 1572864;
  if (idx < 3145728) { cvt4(Wih1 + idx, wih1b + idx); return; }
  idx -= 3145728;
  if (idx < 1572864) { cvt4(Whh1 + idx, whh1b + idx); return; }
  idx -= 1572864;
  if (idx < 2097152) { cvt4(hidden + idx, hbf + idx); return; }
  idx -= 2097152;
  if (idx < 25755648) {          // Wproj padded [50304][512]
    long long row = idx >> 9, col = idx & 511;
    if (row < Vv) cvt4(Wproj + row * 512 + col, wprojb + idx);
    else *(uint2*)(wprojb + idx) = make_uint2(0u, 0u);
    return;
  }
  idx -= 25755648;
  if (idx < VP) {
    float4 v;
    v.x = (idx + 0 < Vv) ? bproj[idx + 0] : -1e30f;
    v.y = (idx + 1 < Vv) ? bproj[idx + 1] : -1e30f;
    v.z = (idx + 2 < Vv) ? bproj[idx + 2] : -1e30f;
    v.w = (idx + 3 < Vv) ? bproj[idx + 3] : -1e30f;
    *(float4*)(bprojp + idx) = v;
  }
}

__global__ void gather_embed(const int* x, const float* embed, unsigned short* xe) {
  int b = blockIdx.x, t = threadIdx.x;
  int tok = x[b];
  float2 v = *(const float2*)(embed + (size_t)tok * 512 + t * 2);
  unsigned int o = ((unsigned int)f2bf(v.y) << 16) | f2bf(v.x);
  *(unsigned int*)((unsigned short*)xe + (size_t)b * 512 + t * 2) = o;
}

// ---------------- softmax normalization --------------------------------------------------------
__global__ void rowsum_inv(const float* partial, float* inv) {
  int row = blockIdx.x, tid = threadIdx.x;   // 128 threads
  float s = 0.f;
  for (int c = tid; c < NPB; c += 128) s += partial[(size_t)row * NPB + c];
  __shared__ float tmp[128];
  tmp[tid] = s;
  __syncthreads();
  for (int off = 64; off > 0; off >>= 1) {
    if (tid < off) tmp[tid] += tmp[tid + off];
    __syncthreads();
  }
  if (tid == 0) inv[row] = 1.0f / tmp[0];
}

// Flat-index normalize+expand: thread f owns probs[4f..4f+4) -> aligned float4 store, no tail.
__global__ __launch_bounds__(256) void scale_expand(const unsigned short* stash, const float* inv,
                                                    float* probs) {
  const unsigned int nquad = 12865792u;        // (1024*50257)/4 exactly
  const unsigned int step = gridDim.x * 256u;
  for (unsigned int f = blockIdx.x * 256u + threadIdx.x; f < nquad; f += step) {
    unsigned int e0 = f * 4u;                  // flat element index, < 2^26
    unsigned int row = e0 / (unsigned int)Vv;  // magic-multiply division
    int col = (int)(e0 - row * (unsigned int)Vv);
    float4 o;
    if (col + 4 <= Vv) {                       // single-row fast path
      float s = inv[row];
      const unsigned short* sp = stash + (size_t)row * VP + col;
      if ((col & 1) == 0) {                    // 4B-aligned: two uint loads (row-uniform branch)
        unsigned int u0 = *(const unsigned int*)sp;
        unsigned int u1 = *(const unsigned int*)(sp + 2);
        o.x = bf2f((unsigned short)u0) * s;
        o.y = bf2f((unsigned short)(u0 >> 16)) * s;
        o.z = bf2f((unsigned short)u1) * s;
        o.w = bf2f((unsigned short)(u1 >> 16)) * s;
      } else {
        o.x = bf2f(sp[0]) * s; o.y = bf2f(sp[1]) * s;
        o.z = bf2f(sp[2]) * s; o.w = bf2f(sp[3]) * s;
      }
    } else {                                   // row-straddling thread (1023 total)
      float vals[4];
#pragma unroll
      for (int k = 0; k < 4; ++k) {
        unsigned int e = e0 + k;
        unsigned int rk = e / (unsigned int)Vv;
        int ck = (int)(e - rk * (unsigned int)Vv);
        vals[k] = bf2f(stash[(size_t)rk * VP + ck]) * inv[rk];
      }
      o.x = vals[0]; o.y = vals[1]; o.z = vals[2]; o.w = vals[3];
    }
    *(float4*)(probs + e0) = o;                // always 16B-aligned, fully coalesced
  }
}

// ---------------- host-side launch -------------------------------------------------------------
extern "C" void kernel_launch(void* const* d_in, const int* in_sizes, int n_in,
                              void* d_out, int out_size, void* d_ws, size_t ws_size,
                              hipStream_t stream) {
  const int*   x      = (const int*)d_in[0];
  const float* hidden = (const float*)d_in[1];
  const float* embed  = (const float*)d_in[2];
  const float* Wih0   = (const float*)d_in[3];
  const float* Whh0   = (const float*)d_in[4];
  const float* bih0   = (const float*)d_in[5];
  const float* bhh0   = (const float*)d_in[6];
  const float* Wih1   = (const float*)d_in[7];
  const float* Whh1   = (const float*)d_in[8];
  const float* bih1   = (const float*)d_in[9];
  const float* bhh1   = (const float*)d_in[10];
  const float* Wproj  = (const float*)d_in[11];
  const float* bproj  = (const float*)d_in[12];
  float* out = (float*)d_out;

  char* ws = (char*)d_ws;
  unsigned short* wih0b  = (unsigned short*)(ws);
  unsigned short* whh0b  = (unsigned short*)(ws + 3145728);
  unsigned short* wih1b  = (unsigned short*)(ws + 6291456);
  unsigned short* whh1b  = (unsigned short*)(ws + 12582912);
  unsigned short* hbf    = (unsigned short*)(ws + 15728640);
  unsigned short* wprojb = (unsigned short*)(ws + 19922944);
  float*          bprojp = (float*)(ws + 71434240);
  unsigned short* xe     = (unsigned short*)(ws + 71635456);
  unsigned short* inp1   = (unsigned short*)(ws + 72684032);
  unsigned short* hb1    = (unsigned short*)(ws + 74781184);
  float*          Cbuf   = (float*)(ws + 75829760);
  float*          partial= (float*)(ws + 100995584);
  float*          inv    = (float*)(ws + 102605312);
  unsigned short* stash  = (unsigned short*)(ws + 102609408);
  const size_t NEED_STASH = 102609408ull + (size_t)Bsz * VP * 2ull;   // ~205.6 MB

  float* out_newh = out + 51463168ll;   // 1024*50257

  convert_all<<<34930, 256, 0, stream>>>(Wih0, Whh0, Wih1, Whh1, hidden, Wproj, bproj,
                                         wih0b, whh0b, wih1b, whh1b, hbf, wprojb, bprojp);
  gather_embed<<<1024, 256, 0, stream>>>(x, embed, xe);

  // layer 0
  GemmDesc d0;
  d0.A[0] = xe;  d0.A[1] = xe;
  d0.A[2] = hbf; d0.A[3] = hbf + 524288;
  d0.Bw[0] = wih0b; d0.Bw[1] = wih0b + 786432;
  d0.Bw[2] = whh0b; d0.Bw[3] = whh0b + 786432;
  d0.bias[0] = bih0; d0.bias[1] = bih0 + 1536;
  d0.bias[2] = bhh0; d0.bias[3] = bhh0 + 1536;
  d0.C[0] = Cbuf;             d0.C[1] = Cbuf + 1572864;
  d0.C[2] = Cbuf + 2*1572864; d0.C[3] = Cbuf + 3*1572864;
  d0.K[0] = d0.K[1] = d0.K[2] = d0.K[3] = 512;
  gemm_gru_batch<<<dim3(12, 4, 4), 512, 0, stream>>>(d0);
  gru_gates<<<4096, 256, 0, stream>>>(Cbuf, hidden, out_newh, inp1, 0);

  // layer 1
  GemmDesc d1;
  d1.A[0] = inp1; d1.A[1] = inp1;
  d1.A[2] = hbf + 2*524288; d1.A[3] = hbf + 3*524288;
  d1.Bw[0] = wih1b; d1.Bw[1] = wih1b + 1572864;
  d1.Bw[2] = whh1b; d1.Bw[3] = whh1b + 786432;
  d1.bias[0] = bih1; d1.bias[1] = bih1 + 1536;
  d1.bias[2] = bhh1; d1.bias[3] = bhh1 + 1536;
  d1.C[0] = Cbuf;             d1.C[1] = Cbuf + 1572864;
  d1.C[2] = Cbuf + 2*1572864; d1.C[3] = Cbuf + 3*1572864;
  d1.K[0] = d1.K[1] = 1024; d1.K[2] = d1.K[3] = 512;
  gemm_gru_batch<<<dim3(12, 4, 4), 512, 0, stream>>>(d1);
  gru_gates<<<4096, 256, 0, stream>>>(Cbuf, hidden, out_newh, hb1, 1);

  // projection + softmax
  if (ws_size >= NEED_STASH) {
    gemm_proj<0><<<1572, 512, 0, stream>>>(hb1, wprojb, bprojp, stash, out, partial, inv);
    rowsum_inv<<<1024, 128, 0, stream>>>(partial, inv);
    scale_expand<<<8192, 256, 0, stream>>>(stash, inv, out);
  } else {
    gemm_proj<1><<<1572, 512, 0, stream>>>(hb1, wprojb, bprojp, stash, out, partial, inv);
    rowsum_inv<<<1024, 128, 0, stream>>>(partial, inv);
    gemm_proj<2><<<1572, 512, 0, stream>>>(hb1, wprojb, bprojp, stash, out, partial, inv);
  }
}